// Round 8
// baseline (276.264 us; speedup 1.0000x reference)
//
#include <hip/hip_runtime.h>
#include <hip/hip_bf16.h>

#define EPSV 1e-5f
#define CB   1024          // nodes per coarse bucket
#define NBC  98            // ceil(100000/1024)

typedef __hip_bfloat16 bf16;
typedef __attribute__((ext_vector_type(8))) short short8v;
typedef __attribute__((ext_vector_type(4))) float f32x4v;

__device__ inline void atomAddG(float* p, float v) { unsafeAtomicAdd(p, v); }
__device__ inline unsigned short f2bf(float v) {
    bf16 h = __float2bfloat16(v);
    return *reinterpret_cast<unsigned short*>(&h);
}
__device__ inline float bfu(unsigned short u) {
    return __uint_as_float(((unsigned int)u) << 16);
}

// ---------------- coarse histogram (LDS-aggregated, 98 bins) ----------------
__global__ __launch_bounds__(256) void bhist_kernel(
    const int* __restrict__ edges, int* __restrict__ gbcnt, int E)
{
    __shared__ int lh[NBC];
    const int t = threadIdx.x;
    if (t < NBC) lh[t] = 0;
    __syncthreads();
    const int base = blockIdx.x * 4096;
    #pragma unroll
    for (int i = 0; i < 16; ++i) {
        int e = base + i * 256 + t;
        if (e < E) atomicAdd(&lh[edges[E + e] >> 10], 1);
    }
    __syncthreads();
    if (t < NBC) {
        int c = lh[t];
        if (c) atomicAdd(&gbcnt[t], c);
    }
}

// ------- coarse scan (single block): bbase exclusive + cursor copy -------
__global__ __launch_bounds__(128) void bscan_kernel(
    const int* __restrict__ gbcnt, int* __restrict__ bbase,
    int* __restrict__ gcursor, int E)
{
    __shared__ int l[128];
    const int t = threadIdx.x;
    int v = (t < NBC) ? gbcnt[t] : 0;
    l[t] = v;
    __syncthreads();
    for (int o = 1; o < 128; o <<= 1) {
        int add = (t >= o) ? l[t - o] : 0;
        __syncthreads();
        l[t] += add;
        __syncthreads();
    }
    if (t < NBC) {
        int off = l[t] - v;
        bbase[t] = off;
        gcursor[t] = off;
    }
    if (t == 0) bbase[NBC] = E;
}

// ------- coarse fill: pk = (src<<10)|(dst&1023), grouped by coarse bucket -------
__global__ __launch_bounds__(256) void bfill_kernel(
    const int* __restrict__ edges, int* __restrict__ gcursor,
    int* __restrict__ pk, int E)
{
    __shared__ int lh[NBC];
    __shared__ int lbase[NBC];
    const int t = threadIdx.x;
    if (t < NBC) lh[t] = 0;
    __syncthreads();
    const int base = blockIdx.x * 4096;
    int dv[16];
    #pragma unroll
    for (int i = 0; i < 16; ++i) {
        int e = base + i * 256 + t;
        dv[i] = (e < E) ? edges[E + e] : -1;
        if (dv[i] >= 0) atomicAdd(&lh[dv[i] >> 10], 1);
    }
    __syncthreads();
    if (t < NBC) {
        int c = lh[t];
        lbase[t] = c ? atomicAdd(&gcursor[t], c) : 0;
        lh[t] = 0;
    }
    __syncthreads();
    #pragma unroll
    for (int i = 0; i < 16; ++i) {
        int e = base + i * 256 + t;
        if (dv[i] >= 0) {
            int s = edges[e];
            int b = dv[i] >> 10;
            int pos = lbase[b] + atomicAdd(&lh[b], 1);
            pk[pos] = (s << 10) | (dv[i] & 1023);
        }
    }
}

// ---- per-coarse-bucket sort: rowstart + srcs (writes stay in the bucket's
// ---- contiguous window) + fused x-gather -> agg1. 98 blocks x 1024 threads. ----
__global__ __launch_bounds__(1024) void bsortB_kernel(
    const int* __restrict__ pk, const int* __restrict__ bbase,
    const float* __restrict__ x,
    int* __restrict__ rowstart, int* __restrict__ srcs,
    float* __restrict__ agg1, int N, int E)
{
    __shared__ int lcnt[CB];
    __shared__ int lscan[CB];
    __shared__ float accx[CB * 4];   // 16 KB
    const int t = threadIdx.x;
    const int b = blockIdx.x;
    const int e0 = bbase[b], e1 = bbase[b + 1];
    lcnt[t] = 0;
    #pragma unroll
    for (int i = 0; i < 4; ++i) accx[i * CB + t] = 0.f;
    __syncthreads();
    for (int e = e0 + t; e < e1; e += 1024) atomicAdd(&lcnt[pk[e] & 1023], 1);
    __syncthreads();
    lscan[t] = lcnt[t];
    __syncthreads();
    for (int o = 1; o < CB; o <<= 1) {
        int add = (t >= o) ? lscan[t - o] : 0;
        __syncthreads();
        lscan[t] += add;
        __syncthreads();
    }
    const int n0 = b * CB;
    int excl = lscan[t] - lcnt[t];
    int n = n0 + t;
    if (n <= N) rowstart[n] = e0 + excl;
    lscan[t] = excl;
    lcnt[t] = 0;
    __syncthreads();
    for (int e = e0 + t; e < e1; e += 1024) {
        int v = pk[e];
        int ld = v & 1023;
        int s = v >> 10;
        int pos = atomicAdd(&lcnt[ld], 1);
        srcs[e0 + lscan[ld] + pos] = s;
        atomicAdd(&accx[ld * 4 + 0], x[s * 3 + 0]);
        atomicAdd(&accx[ld * 4 + 1], x[s * 3 + 1]);
        atomicAdd(&accx[ld * 4 + 2], x[s * 3 + 2]);
    }
    __syncthreads();
    for (int i = t; i < CB * 3; i += 1024) {
        int nl = i / 3, c = i - nl * 3;
        int nn = n0 + nl;
        if (nn < N) agg1[nn * 3 + c] = accx[nl * 4 + c];
    }
}

// ------- graph boundaries from sorted membership: gstart[g] for g=0..64 -------
__global__ __launch_bounds__(256) void bounds_kernel(
    const int* __restrict__ membership, int* __restrict__ gstart, int N)
{
    int n = blockIdx.x * 256 + threadIdx.x;
    if (n > N) return;
    int mp = (n == 0) ? -1 : membership[n - 1];
    int mc = (n == N) ? 64 : membership[n];
    for (int g = mp + 1; g <= mc; ++g) gstart[g] = n;
}

// ------- layer 1 dense: u1b = bf16(relu(agg1@W_rel1 + b_rel1 + x@W_root1)); stats -------
__global__ __launch_bounds__(256) void layer1_kernel(
    const float* __restrict__ x, const float* __restrict__ agg1,
    const float* __restrict__ W_rel1, const float* __restrict__ b_rel1,
    const float* __restrict__ W_root1,
    unsigned short* __restrict__ u1b, float* __restrict__ sums, float* __restrict__ sumsq,
    int N)
{
    const int t = threadIdx.x;
    const int f = t & 63, r4 = t >> 6;
    const float wr0 = W_rel1[f], wr1 = W_rel1[64 + f], wr2 = W_rel1[128 + f];
    const float wo0 = W_root1[f], wo1 = W_root1[64 + f], wo2 = W_root1[128 + f];
    const float bb = b_rel1[f];
    float ps = 0.f, pq = 0.f;
    const int base = blockIdx.x * 128;
    for (int i = r4; i < 128; i += 4) {
        int n = base + i;
        if (n >= N) break;
        float a0 = agg1[n * 3 + 0], a1 = agg1[n * 3 + 1], a2 = agg1[n * 3 + 2];
        float x0 = x[n * 3 + 0], x1 = x[n * 3 + 1], x2 = x[n * 3 + 2];
        float v = bb;
        v = fmaf(a0, wr0, v); v = fmaf(a1, wr1, v); v = fmaf(a2, wr2, v);
        v = fmaf(x0, wo0, v); v = fmaf(x1, wo1, v); v = fmaf(x2, wo2, v);
        v = fmaxf(v, 0.f);
        u1b[n * 64 + f] = f2bf(v);
        ps += v; pq += v * v;
    }
    __shared__ float lsum[4][64], lsq[4][64];
    lsum[r4][f] = ps; lsq[r4][f] = pq;
    __syncthreads();
    if (r4 == 0) {
        float s = lsum[0][f] + lsum[1][f] + lsum[2][f] + lsum[3][f];
        float q = lsq[0][f] + lsq[1][f] + lsq[2][f] + lsq[3][f];
        atomAddG(&sums[f], s);
        atomAddG(&sumsq[f], q);
    }
}

// ------------- BN scale/shift for BN2 (fc1 consumes) -------------
__global__ void bnscale_kernel(const float* __restrict__ sums, const float* __restrict__ sumsq,
                               const float* __restrict__ g, const float* __restrict__ b,
                               float invn, int C,
                               float* __restrict__ scale, float* __restrict__ shift)
{
    int f = blockIdx.x * blockDim.x + threadIdx.x;
    if (f >= C) return;
    float m = sums[f] * invn;
    float v = sumsq[f] * invn - m * m;
    float sc = g[f] * rsqrtf(v + EPSV);
    scale[f] = sc;
    shift[f] = b[f] - m * sc;
}

// ---- fused BN1-stats + weight fold: W' = bf16(diag(sc1)W), c = sh1·W (+b_rel2) ----
__global__ __launch_bounds__(256) void bnfold_kernel(
    const float* __restrict__ sums1, const float* __restrict__ sumsq1,
    const float* __restrict__ g1, const float* __restrict__ b1,
    const float* __restrict__ W_rel2, const float* __restrict__ W_root2,
    const float* __restrict__ b_rel2,
    unsigned short* __restrict__ wrelp, unsigned short* __restrict__ wrootp,
    float* __restrict__ crel, float* __restrict__ croot, float invn)
{
    __shared__ float lsc[64], lsh[64];
    __shared__ float r1[4][64], r2[4][64];
    const int t = threadIdx.x, f = t & 63, kg = t >> 6;
    if (t < 64) {
        float m = sums1[t] * invn;
        float v = sumsq1[t] * invn - m * m;
        float sc = g1[t] * rsqrtf(v + EPSV);
        lsc[t] = sc;
        lsh[t] = b1[t] - m * sc;
    }
    __syncthreads();
    float c1 = 0.f, c2 = 0.f;
    for (int k = kg * 16; k < kg * 16 + 16; ++k) {
        float sc = lsc[k], sh = lsh[k];
        float w1 = W_rel2[k * 64 + f], w2 = W_root2[k * 64 + f];
        wrelp[k * 64 + f] = f2bf(sc * w1);
        wrootp[k * 64 + f] = f2bf(sc * w2);
        c1 = fmaf(sh, w1, c1); c2 = fmaf(sh, w2, c2);
    }
    r1[kg][f] = c1; r2[kg][f] = c2;
    __syncthreads();
    if (kg == 0) {
        crel[f]  = r1[0][f] + r1[1][f] + r1[2][f] + r1[3][f];
        croot[f] = r2[0][f] + r2[1][f] + r2[2][f] + r2[3][f] + b_rel2[f];
    }
}

// ---- MFMA transform: t = u1b@W_rel' + crel; p = u1b@W_root' + croot (bf16 out) ----
__global__ __launch_bounds__(256) void mfma_transform_kernel(
    const unsigned short* __restrict__ u1b,
    const unsigned short* __restrict__ wrelp, const unsigned short* __restrict__ wrootp,
    const float* __restrict__ crel, const float* __restrict__ croot,
    unsigned short* __restrict__ tb, unsigned short* __restrict__ pb, int NT)
{
    const int wid = (blockIdx.x * blockDim.x + threadIdx.x) >> 6;
    const int lane = threadIdx.x & 63;
    const int q = lane >> 4, r = lane & 15;

    short8v Bf[2][8];
    float cadd[8];
    #pragma unroll
    for (int kc = 0; kc < 2; ++kc) {
        #pragma unroll
        for (int ft = 0; ft < 8; ++ft) {
            const unsigned short* W = (ft < 4) ? wrelp : wrootp;
            const int f0 = (ft & 3) * 16;
            short8v bb;
            #pragma unroll
            for (int j = 0; j < 8; ++j) {
                int k = 32 * kc + 8 * q + j;
                bb[j] = (short)W[k * 64 + f0 + r];
            }
            Bf[kc][ft] = bb;
        }
    }
    #pragma unroll
    for (int ft = 0; ft < 8; ++ft)
        cadd[ft] = (ft < 4) ? crel[(ft & 3) * 16 + r] : croot[(ft & 3) * 16 + r];

    const int totalWaves = (gridDim.x * blockDim.x) >> 6;
    for (int tile = wid; tile < NT; tile += totalWaves) {
        const int n0 = tile * 16;
        short8v A0 = *(const short8v*)&u1b[(n0 + r) * 64 + 8 * q];
        short8v A1 = *(const short8v*)&u1b[(n0 + r) * 64 + 32 + 8 * q];
        #pragma unroll
        for (int ft = 0; ft < 8; ++ft) {
            f32x4v d = {0.f, 0.f, 0.f, 0.f};
            d = __builtin_amdgcn_mfma_f32_16x16x32_bf16(A0, Bf[0][ft], d, 0, 0, 0);
            d = __builtin_amdgcn_mfma_f32_16x16x32_bf16(A1, Bf[1][ft], d, 0, 0, 0);
            unsigned short* O = (ft < 4) ? tb : pb;
            const int f0 = (ft & 3) * 16;
            const float ca = cadd[ft];
            #pragma unroll
            for (int rr = 0; rr < 4; ++rr) {
                int n = n0 + 4 * q + rr;
                O[n * 64 + f0 + r] = f2bf(d[rr] + ca);
            }
        }
    }
}

// ---- gather+pool, 2-row interleaved: u2[n]=relu(sum t[src]+p[n]); stats; pool ----
__global__ __launch_bounds__(256, 8) void gatherpool_kernel(
    const unsigned short* __restrict__ tb, const unsigned short* __restrict__ pb,
    const int* __restrict__ rowstart, const int* __restrict__ srcs,
    const int* __restrict__ membership,
    float* __restrict__ pooled, float* __restrict__ sums, float* __restrict__ sumsq,
    int N, int chunk)
{
    __shared__ float red[4][64];
    const int tid = threadIdx.x;
    const int w = tid >> 6, f = tid & 63;
    const int gw = __builtin_amdgcn_readfirstlane(blockIdx.x * 4 + w);
    const int n0 = gw * chunk;
    const int n1 = min(N, n0 + chunk);
    float ps = 0.f, pq = 0.f, pacc = 0.f;
    int curg = (n0 < N) ? membership[n0] : -1;

    for (int n = n0; n < n1; n += 2) {
        const bool two = (n + 1 < n1);
        int sA0 = rowstart[n], sA1 = rowstart[n + 1];
        int sB1 = two ? rowstart[n + 2] : sA1;
        int degA = sA1 - sA0, degB = sB1 - sA1;
        float accA = bfu(pb[n * 64 + f]);
        float accB = two ? bfu(pb[(n + 1) * 64 + f]) : 0.f;

        int mA = degA & ~7, mB = degB & ~7;
        int m = min(mA, mB);
        int k = 0;
        for (; k < m; k += 8) {
            float va[8], vb[8];
            #pragma unroll
            for (int u = 0; u < 8; ++u) va[u] = bfu(tb[srcs[sA0 + k + u] * 64 + f]);
            #pragma unroll
            for (int u = 0; u < 8; ++u) vb[u] = bfu(tb[srcs[sA1 + k + u] * 64 + f]);
            accA += ((va[0] + va[1]) + (va[2] + va[3])) + ((va[4] + va[5]) + (va[6] + va[7]));
            accB += ((vb[0] + vb[1]) + (vb[2] + vb[3])) + ((vb[4] + vb[5]) + (vb[6] + vb[7]));
        }
        for (int ka = k; ka < mA; ka += 8) {
            float va[8];
            #pragma unroll
            for (int u = 0; u < 8; ++u) va[u] = bfu(tb[srcs[sA0 + ka + u] * 64 + f]);
            accA += ((va[0] + va[1]) + (va[2] + va[3])) + ((va[4] + va[5]) + (va[6] + va[7]));
        }
        for (int kb = k; kb < mB; kb += 8) {
            float vb[8];
            #pragma unroll
            for (int u = 0; u < 8; ++u) vb[u] = bfu(tb[srcs[sA1 + kb + u] * 64 + f]);
            accB += ((vb[0] + vb[1]) + (vb[2] + vb[3])) + ((vb[4] + vb[5]) + (vb[6] + vb[7]));
        }
        for (int ka = mA; ka < degA; ++ka) accA += bfu(tb[srcs[sA0 + ka] * 64 + f]);
        for (int kb = mB; kb < degB; ++kb) accB += bfu(tb[srcs[sA1 + kb] * 64 + f]);

        accA = fmaxf(accA, 0.f);
        ps += accA; pq += accA * accA;
        int gA = membership[n];
        if (gA != curg) {
            atomAddG(&pooled[curg * 64 + f], pacc);
            pacc = 0.f; curg = gA;
        }
        pacc += accA;

        if (two) {
            accB = fmaxf(accB, 0.f);
            ps += accB; pq += accB * accB;
            int gB = membership[n + 1];
            if (gB != curg) {
                atomAddG(&pooled[curg * 64 + f], pacc);
                pacc = 0.f; curg = gB;
            }
            pacc += accB;
        }
    }
    if (curg >= 0) atomAddG(&pooled[curg * 64 + f], pacc);

    red[w][f] = ps;
    __syncthreads();
    if (w == 0) atomAddG(&sums[f], red[0][f] + red[1][f] + red[2][f] + red[3][f]);
    __syncthreads();
    red[w][f] = pq;
    __syncthreads();
    if (w == 0) atomAddG(&sumsq[f], red[0][f] + red[1][f] + red[2][f] + red[3][f]);
}

// ---- head fused: pm = BN2(pooled/cnt); z = BN3(relu(pm@W_fc1+b_fc1)); out = z@W_fc2+b ----
__global__ __launch_bounds__(1024) void fc12_kernel(
    const float* __restrict__ pooled, const int* __restrict__ gstart,
    const float* __restrict__ scale2, const float* __restrict__ shift2,
    const float* __restrict__ W_fc1, const float* __restrict__ b_fc1,
    const float* __restrict__ g3, const float* __restrict__ b3,
    const float* __restrict__ W_fc2, const float* __restrict__ b_fc2,
    float* __restrict__ z, float* __restrict__ out)
{
    __shared__ float pm[4096];
    __shared__ float reds[4][256], redq[4][256];
    __shared__ float lsc[256], lsh[256];
    const int t = threadIdx.x;
    for (int i = t; i < 4096; i += 1024) {
        int g = i >> 6, f = i & 63;
        float c = fmaxf((float)(gstart[g + 1] - gstart[g]), 1.0f);
        pm[i] = fmaf(pooled[i] / c, scale2[f], shift2[f]);
    }
    __syncthreads();
    const int col = t & 255, grp = t >> 8;
    float acc[16];
    const float bc = b_fc1[col];
    #pragma unroll
    for (int g = 0; g < 16; ++g) acc[g] = bc;
    for (int k = 0; k < 64; ++k) {
        float wv = W_fc1[k * 256 + col];
        #pragma unroll
        for (int g = 0; g < 16; ++g)
            acc[g] = fmaf(pm[(grp * 16 + g) * 64 + k], wv, acc[g]);
    }
    float s = 0.f, q = 0.f;
    #pragma unroll
    for (int g = 0; g < 16; ++g) {
        acc[g] = fmaxf(acc[g], 0.f);
        s += acc[g]; q += acc[g] * acc[g];
    }
    reds[grp][col] = s; redq[grp][col] = q;
    __syncthreads();
    if (grp == 0) {
        float S = reds[0][col] + reds[1][col] + reds[2][col] + reds[3][col];
        float Q = redq[0][col] + redq[1][col] + redq[2][col] + redq[3][col];
        float m = S * (1.0f / 64.0f);
        float v = Q * (1.0f / 64.0f) - m * m;
        float sc = g3[col] * rsqrtf(v + EPSV);
        lsc[col] = sc;
        lsh[col] = b3[col] - m * sc;
    }
    __syncthreads();
    float sc = lsc[col], sh = lsh[col];
    #pragma unroll
    for (int g = 0; g < 16; ++g)
        z[(grp * 16 + g) * 256 + col] = fmaf(acc[g], sc, sh);
    __syncthreads();
    if (t < 640) {
        int g = t / 10, o = t % 10;
        float a = b_fc2[o];
        for (int c = 0; c < 256; ++c)
            a = fmaf(z[g * 256 + c], W_fc2[c * 10 + o], a);
        out[g * 10 + o] = a;
    }
}

extern "C" void kernel_launch(void* const* d_in, const int* in_sizes, int n_in,
                              void* d_out, int out_size, void* d_ws, size_t ws_size,
                              hipStream_t stream) {
    const int N = 100000, E = 1600000;

    const float* x          = (const float*)d_in[0];
    const int*   membership = (const int*)d_in[1];
    const int*   edges      = (const int*)d_in[2];
    const float* W_rel1     = (const float*)d_in[3];
    const float* b_rel1     = (const float*)d_in[4];
    const float* W_root1    = (const float*)d_in[5];
    const float* W_rel2     = (const float*)d_in[6];
    const float* b_rel2     = (const float*)d_in[7];
    const float* W_root2    = (const float*)d_in[8];
    const float* g1         = (const float*)d_in[9];
    const float* b1         = (const float*)d_in[10];
    const float* g2         = (const float*)d_in[11];
    const float* b2         = (const float*)d_in[12];
    const float* W_fc1      = (const float*)d_in[13];
    const float* b_fc1      = (const float*)d_in[14];
    const float* g3         = (const float*)d_in[15];
    const float* b3         = (const float*)d_in[16];
    const float* W_fc2      = (const float*)d_in[17];
    const float* b_fc2      = (const float*)d_in[18];

    // workspace layout (4B elements) — same offsets as round 7
    int*   wsi      = (int*)d_ws;
    float* wsf      = (float*)d_ws;
    int*   gbcnt    = wsi + 0;        // 98 used (784 zeroed)
    float* stats    = wsf + 784;      // 512
    float* pooled   = wsf + 1296;     // 4096
    int*   bbase    = wsi + 5392;     // 99
    int*   gcursor  = wsi + 6192;     // 98
    int*   gstart   = wsi + 6976;     // 128
    int*   rowstart = wsi + 7104;     // 100001
    int*   pk       = wsi + 107168;   // 1600000
    int*   srcs     = wsi + 1707168;  // 1600000
    float* agg1     = wsf + 3307168;  // 300032
    unsigned short* u1b = (unsigned short*)(wsf + 3607200);
    unsigned short* tb  = (unsigned short*)(wsf + 6807200);
    unsigned short* pb  = (unsigned short*)(wsf + 10007200);
    unsigned short* wrelp  = (unsigned short*)(wsf + 13207200);
    unsigned short* wrootp = (unsigned short*)(wsf + 13209248);
    float* crel     = wsf + 13211296; // 64
    float* croot    = wsf + 13211360; // 64
    float* z        = wsf + 13211424; // 16384

    float* sums1  = stats + 0;
    float* sumsq1 = stats + 64;
    float* sums2  = stats + 128;
    float* sumsq2 = stats + 192;
    float* scale2 = stats + 384;
    float* shift2 = stats + 448;

    hipMemsetAsync(d_ws, 0, (size_t)(784 + 512 + 4096) * 4, stream);

    // two-level CSR build
    const int EB = (E + 4095) / 4096;  // 391
    bhist_kernel<<<EB, 256, 0, stream>>>(edges, gbcnt, E);
    bscan_kernel<<<1, 128, 0, stream>>>(gbcnt, bbase, gcursor, E);
    bfill_kernel<<<EB, 256, 0, stream>>>(edges, gcursor, pk, E);
    bsortB_kernel<<<NBC, 1024, 0, stream>>>(pk, bbase, x, rowstart, srcs, agg1, N, E);
    bounds_kernel<<<(N + 256) / 256, 256, 0, stream>>>(membership, gstart, N);

    // layer 1 dense + BN1-stats
    layer1_kernel<<<(N + 127) / 128, 256, 0, stream>>>(
        x, agg1, W_rel1, b_rel1, W_root1, u1b, sums1, sumsq1, N);

    // fused BN1 scale/shift + weight fold, then MFMA transform
    bnfold_kernel<<<1, 256, 0, stream>>>(sums1, sumsq1, g1, b1,
                                         W_rel2, W_root2, b_rel2,
                                         wrelp, wrootp, crel, croot, 1.0f / N);
    mfma_transform_kernel<<<512, 256, 0, stream>>>(
        u1b, wrelp, wrootp, crel, croot, tb, pb, N / 16);

    // streaming bf16 gather + pool (2-row interleaved)
    {
        const int GRID2 = 2048;
        int chunk = (N + GRID2 * 4 - 1) / (GRID2 * 4);  // 13
        gatherpool_kernel<<<GRID2, 256, 0, stream>>>(
            tb, pb, rowstart, srcs, membership, pooled, sums2, sumsq2, N, chunk);
    }
    bnscale_kernel<<<1, 64, 0, stream>>>(sums2, sumsq2, g2, b2, 1.0f / N, 64, scale2, shift2);

    // fused head
    fc12_kernel<<<1, 1024, 0, stream>>>(pooled, gstart, scale2, shift2,
                                        W_fc1, b_fc1, g3, b3, W_fc2, b_fc2,
                                        z, (float*)d_out);
}

// Round 9
// 265.004 us; speedup vs baseline: 1.0425x; 1.0425x over previous
//
#include <hip/hip_runtime.h>
#include <hip/hip_bf16.h>

#define EPSV 1e-5f
#define BKT 128            // nodes per bucket
#define NB  782            // ceil(100000/128)

typedef __hip_bfloat16 bf16;
typedef __attribute__((ext_vector_type(8))) short short8v;
typedef __attribute__((ext_vector_type(4))) float f32x4v;

__device__ inline void atomAddG(float* p, float v) { unsafeAtomicAdd(p, v); }
__device__ inline unsigned short f2bf(float v) {
    bf16 h = __float2bfloat16(v);
    return *reinterpret_cast<unsigned short*>(&h);
}

// ---------------- bucket histogram (LDS-aggregated, 782 bins) ----------------
__global__ __launch_bounds__(256) void bhist_kernel(
    const int* __restrict__ edges, int* __restrict__ gbcnt, int E)
{
    __shared__ int lh[NB];
    const int t = threadIdx.x;
    for (int i = t; i < NB; i += 256) lh[i] = 0;
    __syncthreads();
    const int base = blockIdx.x * 4096;
    #pragma unroll
    for (int i = 0; i < 16; ++i) {
        int e = base + i * 256 + t;
        if (e < E) atomicAdd(&lh[edges[E + e] >> 7], 1);
    }
    __syncthreads();
    for (int i = t; i < NB; i += 256) {
        int c = lh[i];
        if (c) atomicAdd(&gbcnt[i], c);
    }
}

// ------- bucket scan (single block): bbase exclusive + cursor copy -------
__global__ __launch_bounds__(256) void bscan_kernel(
    const int* __restrict__ gbcnt, int* __restrict__ bbase,
    int* __restrict__ gcursor, int E)
{
    __shared__ int l[256];
    const int t = threadIdx.x;
    int b0 = t * 4;
    int v0 = (b0 + 0 < NB) ? gbcnt[b0 + 0] : 0;
    int v1 = (b0 + 1 < NB) ? gbcnt[b0 + 1] : 0;
    int v2 = (b0 + 2 < NB) ? gbcnt[b0 + 2] : 0;
    int v3 = (b0 + 3 < NB) ? gbcnt[b0 + 3] : 0;
    int tot = v0 + v1 + v2 + v3;
    l[t] = tot;
    __syncthreads();
    for (int o = 1; o < 256; o <<= 1) {
        int add = (t >= o) ? l[t - o] : 0;
        __syncthreads();
        l[t] += add;
        __syncthreads();
    }
    int off = l[t] - tot;
    if (b0 + 0 < NB) { bbase[b0 + 0] = off;                gcursor[b0 + 0] = off; }
    if (b0 + 1 < NB) { bbase[b0 + 1] = off + v0;           gcursor[b0 + 1] = off + v0; }
    if (b0 + 2 < NB) { bbase[b0 + 2] = off + v0 + v1;      gcursor[b0 + 2] = off + v0 + v1; }
    if (b0 + 3 < NB) { bbase[b0 + 3] = off + v0 + v1 + v2; gcursor[b0 + 3] = off + v0 + v1 + v2; }
    if (t == 0) bbase[NB] = E;
}

// ------- bucket fill: pk = (src<<7)|(dst&127), grouped by bucket -------
__global__ __launch_bounds__(256) void bfill_kernel(
    const int* __restrict__ edges, int* __restrict__ gcursor,
    int* __restrict__ pk, int E)
{
    __shared__ int lh[NB];
    __shared__ int lbase[NB];
    const int t = threadIdx.x;
    for (int i = t; i < NB; i += 256) lh[i] = 0;
    __syncthreads();
    const int base = blockIdx.x * 4096;
    int dv[16];
    #pragma unroll
    for (int i = 0; i < 16; ++i) {
        int e = base + i * 256 + t;
        dv[i] = (e < E) ? edges[E + e] : -1;
        if (dv[i] >= 0) atomicAdd(&lh[dv[i] >> 7], 1);
    }
    __syncthreads();
    for (int i = t; i < NB; i += 256) {
        int c = lh[i];
        lbase[i] = c ? atomicAdd(&gcursor[i], c) : 0;
        lh[i] = 0;
    }
    __syncthreads();
    #pragma unroll
    for (int i = 0; i < 16; ++i) {
        int e = base + i * 256 + t;
        if (dv[i] >= 0) {
            int s = edges[e];
            int b = dv[i] >> 7;
            int pos = lbase[b] + atomicAdd(&lh[b], 1);
            pk[pos] = (s << 7) | (dv[i] & 127);
        }
    }
}

// ---- per-bucket fine sort + fused x-gather: CSR rowstart + srcs + agg1 ----
__global__ __launch_bounds__(256) void bsort_kernel(
    const int* __restrict__ pk, const int* __restrict__ bbase,
    const float* __restrict__ x,
    int* __restrict__ rowstart, int* __restrict__ srcs,
    float* __restrict__ agg1, int N, int E)
{
    __shared__ int lcnt[BKT];
    __shared__ int lscan[BKT];
    __shared__ float accx[BKT * 4];
    const int t = threadIdx.x;
    const int b = blockIdx.x;
    const int e0 = bbase[b], e1 = bbase[b + 1];
    if (t < BKT) lcnt[t] = 0;
    for (int i = t; i < BKT * 4; i += 256) accx[i] = 0.f;
    __syncthreads();
    for (int e = e0 + t; e < e1; e += 256) atomicAdd(&lcnt[pk[e] & 127], 1);
    __syncthreads();
    if (t < BKT) lscan[t] = lcnt[t];
    __syncthreads();
    for (int o = 1; o < BKT; o <<= 1) {
        int add = (t < BKT && t >= o) ? lscan[t - o] : 0;
        __syncthreads();
        if (t < BKT) lscan[t] += add;
        __syncthreads();
    }
    const int n0 = b * BKT;
    if (t < BKT) {
        int excl = lscan[t] - lcnt[t];
        lscan[t] = excl;
        int n = n0 + t;
        if (n <= N) rowstart[n] = e0 + excl;   // last bucket's t=32 writes rowstart[N]=E
        lcnt[t] = 0;
    }
    __syncthreads();
    for (int e = e0 + t; e < e1; e += 256) {
        int v = pk[e];
        int ld = v & 127;
        int s = v >> 7;
        int pos = atomicAdd(&lcnt[ld], 1);
        srcs[e0 + lscan[ld] + pos] = s;
        atomicAdd(&accx[ld * 4 + 0], x[s * 3 + 0]);
        atomicAdd(&accx[ld * 4 + 1], x[s * 3 + 1]);
        atomicAdd(&accx[ld * 4 + 2], x[s * 3 + 2]);
    }
    __syncthreads();
    for (int i = t; i < BKT * 3; i += 256) {
        int nl = i / 3, c = i - nl * 3;
        int n = n0 + nl;
        if (n < N) agg1[n * 3 + c] = accx[nl * 4 + c];
    }
}

// ------- graph boundaries from sorted membership: gstart[g] for g=0..64 -------
__global__ __launch_bounds__(256) void bounds_kernel(
    const int* __restrict__ membership, int* __restrict__ gstart, int N)
{
    int n = blockIdx.x * 256 + threadIdx.x;
    if (n > N) return;
    int mp = (n == 0) ? -1 : membership[n - 1];
    int mc = (n == N) ? 64 : membership[n];
    for (int g = mp + 1; g <= mc; ++g) gstart[g] = n;
}

// ------- layer 1 dense: u1b = bf16(relu(agg1@W_rel1 + b_rel1 + x@W_root1)); stats -------
__global__ __launch_bounds__(256) void layer1_kernel(
    const float* __restrict__ x, const float* __restrict__ agg1,
    const float* __restrict__ W_rel1, const float* __restrict__ b_rel1,
    const float* __restrict__ W_root1,
    unsigned short* __restrict__ u1b, float* __restrict__ sums, float* __restrict__ sumsq,
    int N)
{
    const int t = threadIdx.x;
    const int f = t & 63, r4 = t >> 6;
    const float wr0 = W_rel1[f], wr1 = W_rel1[64 + f], wr2 = W_rel1[128 + f];
    const float wo0 = W_root1[f], wo1 = W_root1[64 + f], wo2 = W_root1[128 + f];
    const float bb = b_rel1[f];
    float ps = 0.f, pq = 0.f;
    const int base = blockIdx.x * 128;
    for (int i = r4; i < 128; i += 4) {
        int n = base + i;
        if (n >= N) break;
        float a0 = agg1[n * 3 + 0], a1 = agg1[n * 3 + 1], a2 = agg1[n * 3 + 2];
        float x0 = x[n * 3 + 0], x1 = x[n * 3 + 1], x2 = x[n * 3 + 2];
        float v = bb;
        v = fmaf(a0, wr0, v); v = fmaf(a1, wr1, v); v = fmaf(a2, wr2, v);
        v = fmaf(x0, wo0, v); v = fmaf(x1, wo1, v); v = fmaf(x2, wo2, v);
        v = fmaxf(v, 0.f);
        u1b[n * 64 + f] = f2bf(v);
        ps += v; pq += v * v;
    }
    __shared__ float lsum[4][64], lsq[4][64];
    lsum[r4][f] = ps; lsq[r4][f] = pq;
    __syncthreads();
    if (r4 == 0) {
        float s = lsum[0][f] + lsum[1][f] + lsum[2][f] + lsum[3][f];
        float q = lsq[0][f] + lsq[1][f] + lsq[2][f] + lsq[3][f];
        atomAddG(&sums[f], s);
        atomAddG(&sumsq[f], q);
    }
}

// ------------- BN scale/shift for BN2 (fc12 consumes) -------------
__global__ void bnscale_kernel(const float* __restrict__ sums, const float* __restrict__ sumsq,
                               const float* __restrict__ g, const float* __restrict__ b,
                               float invn, int C,
                               float* __restrict__ scale, float* __restrict__ shift)
{
    int f = blockIdx.x * blockDim.x + threadIdx.x;
    if (f >= C) return;
    float m = sums[f] * invn;
    float v = sumsq[f] * invn - m * m;
    float sc = g[f] * rsqrtf(v + EPSV);
    scale[f] = sc;
    shift[f] = b[f] - m * sc;
}

// ---- fused BN1-stats + weight fold: W' = bf16(diag(sc1)W), c = sh1·W (+b_rel2) ----
__global__ __launch_bounds__(256) void bnfold_kernel(
    const float* __restrict__ sums1, const float* __restrict__ sumsq1,
    const float* __restrict__ g1, const float* __restrict__ b1,
    const float* __restrict__ W_rel2, const float* __restrict__ W_root2,
    const float* __restrict__ b_rel2,
    unsigned short* __restrict__ wrelp, unsigned short* __restrict__ wrootp,
    float* __restrict__ crel, float* __restrict__ croot, float invn)
{
    __shared__ float lsc[64], lsh[64];
    __shared__ float r1[4][64], r2[4][64];
    const int t = threadIdx.x, f = t & 63, kg = t >> 6;
    if (t < 64) {
        float m = sums1[t] * invn;
        float v = sumsq1[t] * invn - m * m;
        float sc = g1[t] * rsqrtf(v + EPSV);
        lsc[t] = sc;
        lsh[t] = b1[t] - m * sc;
    }
    __syncthreads();
    float c1 = 0.f, c2 = 0.f;
    for (int k = kg * 16; k < kg * 16 + 16; ++k) {
        float sc = lsc[k], sh = lsh[k];
        float w1 = W_rel2[k * 64 + f], w2 = W_root2[k * 64 + f];
        wrelp[k * 64 + f] = f2bf(sc * w1);
        wrootp[k * 64 + f] = f2bf(sc * w2);
        c1 = fmaf(sh, w1, c1); c2 = fmaf(sh, w2, c2);
    }
    r1[kg][f] = c1; r2[kg][f] = c2;
    __syncthreads();
    if (kg == 0) {
        crel[f]  = r1[0][f] + r1[1][f] + r1[2][f] + r1[3][f];
        croot[f] = r2[0][f] + r2[1][f] + r2[2][f] + r2[3][f] + b_rel2[f];
    }
}

// ---- MFMA transform: t = u1b@W_rel' + crel; p = u1b@W_root' + croot (bf16 out) ----
__global__ __launch_bounds__(256) void mfma_transform_kernel(
    const unsigned short* __restrict__ u1b,
    const unsigned short* __restrict__ wrelp, const unsigned short* __restrict__ wrootp,
    const float* __restrict__ crel, const float* __restrict__ croot,
    unsigned short* __restrict__ tb, unsigned short* __restrict__ pb, int NT)
{
    const int wid = (blockIdx.x * blockDim.x + threadIdx.x) >> 6;
    const int lane = threadIdx.x & 63;
    const int q = lane >> 4, r = lane & 15;

    short8v Bf[2][8];
    float cadd[8];
    #pragma unroll
    for (int kc = 0; kc < 2; ++kc) {
        #pragma unroll
        for (int ft = 0; ft < 8; ++ft) {
            const unsigned short* W = (ft < 4) ? wrelp : wrootp;
            const int f0 = (ft & 3) * 16;
            short8v bb;
            #pragma unroll
            for (int j = 0; j < 8; ++j) {
                int k = 32 * kc + 8 * q + j;
                bb[j] = (short)W[k * 64 + f0 + r];
            }
            Bf[kc][ft] = bb;
        }
    }
    #pragma unroll
    for (int ft = 0; ft < 8; ++ft)
        cadd[ft] = (ft < 4) ? crel[(ft & 3) * 16 + r] : croot[(ft & 3) * 16 + r];

    const int totalWaves = (gridDim.x * blockDim.x) >> 6;
    for (int tile = wid; tile < NT; tile += totalWaves) {
        const int n0 = tile * 16;
        short8v A0 = *(const short8v*)&u1b[(n0 + r) * 64 + 8 * q];
        short8v A1 = *(const short8v*)&u1b[(n0 + r) * 64 + 32 + 8 * q];
        #pragma unroll
        for (int ft = 0; ft < 8; ++ft) {
            f32x4v d = {0.f, 0.f, 0.f, 0.f};
            d = __builtin_amdgcn_mfma_f32_16x16x32_bf16(A0, Bf[0][ft], d, 0, 0, 0);
            d = __builtin_amdgcn_mfma_f32_16x16x32_bf16(A1, Bf[1][ft], d, 0, 0, 0);
            unsigned short* O = (ft < 4) ? tb : pb;
            const int f0 = (ft & 3) * 16;
            const float ca = cadd[ft];
            #pragma unroll
            for (int rr = 0; rr < 4; ++rr) {
                int n = n0 + 4 * q + rr;
                O[n * 64 + f0 + r] = f2bf(d[rr] + ca);
            }
        }
    }
}

// ---- gather+pool v3: 4 edges/instruction. lane = (q = edge slot, r = feature quad).
// ---- Each lane loads uint2 (4 bf16 feats) of row srcs[j+q]; 8-deep unroll ->
// ---- 32 rows outstanding. shfl_xor(16,32) merges edge groups per node. ----
__global__ __launch_bounds__(256, 8) void gatherpool_kernel(
    const unsigned short* __restrict__ tb, const unsigned short* __restrict__ pb,
    const int* __restrict__ rowstart, const int* __restrict__ srcs,
    const int* __restrict__ membership,
    float* __restrict__ pooled, float* __restrict__ sums, float* __restrict__ sumsq,
    int N, int chunk)
{
    __shared__ float red[4][64];
    const int tid = threadIdx.x;
    const int w = tid >> 6, lane = tid & 63;
    const int q = lane >> 4;          // edge slot 0..3
    const int r = lane & 15;          // feature quad: features 4r..4r+3
    const int gw = blockIdx.x * 4 + w;
    const int n0 = gw * chunk;
    const int n1 = min(N, n0 + chunk);
    float ps0 = 0.f, ps1 = 0.f, ps2 = 0.f, ps3 = 0.f;
    float pq0 = 0.f, pq1 = 0.f, pq2 = 0.f, pq3 = 0.f;
    float pa0 = 0.f, pa1 = 0.f, pa2 = 0.f, pa3 = 0.f;
    int curg = (n0 < N) ? membership[n0] : -1;

    for (int n = n0; n < n1; ++n) {
        int s0 = rowstart[n], s1 = rowstart[n + 1];
        float a0 = 0.f, a1 = 0.f, a2 = 0.f, a3 = 0.f;
        int j = s0;
        for (; j + 31 < s1; j += 32) {
            int idx[8];
            uint2 v[8];
            #pragma unroll
            for (int u = 0; u < 8; ++u) idx[u] = srcs[j + u * 4 + q];
            #pragma unroll
            for (int u = 0; u < 8; ++u)
                v[u] = *(const uint2*)&tb[idx[u] * 64 + r * 4];
            #pragma unroll
            for (int u = 0; u < 8; ++u) {
                a0 += __uint_as_float(v[u].x << 16);
                a1 += __uint_as_float(v[u].x & 0xffff0000u);
                a2 += __uint_as_float(v[u].y << 16);
                a3 += __uint_as_float(v[u].y & 0xffff0000u);
            }
        }
        for (; j + 3 < s1; j += 4) {
            int src = srcs[j + q];
            uint2 vv = *(const uint2*)&tb[src * 64 + r * 4];
            a0 += __uint_as_float(vv.x << 16);
            a1 += __uint_as_float(vv.x & 0xffff0000u);
            a2 += __uint_as_float(vv.y << 16);
            a3 += __uint_as_float(vv.y & 0xffff0000u);
        }
        int rem = s1 - j;
        if (q < rem) {
            int src = srcs[j + q];
            uint2 vv = *(const uint2*)&tb[src * 64 + r * 4];
            a0 += __uint_as_float(vv.x << 16);
            a1 += __uint_as_float(vv.x & 0xffff0000u);
            a2 += __uint_as_float(vv.y << 16);
            a3 += __uint_as_float(vv.y & 0xffff0000u);
        }
        // merge edge-slot groups (lanes xor 16, 32)
        a0 += __shfl_xor(a0, 16); a0 += __shfl_xor(a0, 32);
        a1 += __shfl_xor(a1, 16); a1 += __shfl_xor(a1, 32);
        a2 += __shfl_xor(a2, 16); a2 += __shfl_xor(a2, 32);
        a3 += __shfl_xor(a3, 16); a3 += __shfl_xor(a3, 32);

        if (q == 0) {
            uint2 pv = *(const uint2*)&pb[n * 64 + r * 4];
            a0 = fmaxf(a0 + __uint_as_float(pv.x << 16), 0.f);
            a1 = fmaxf(a1 + __uint_as_float(pv.x & 0xffff0000u), 0.f);
            a2 = fmaxf(a2 + __uint_as_float(pv.y << 16), 0.f);
            a3 = fmaxf(a3 + __uint_as_float(pv.y & 0xffff0000u), 0.f);
            ps0 += a0; pq0 += a0 * a0;
            ps1 += a1; pq1 += a1 * a1;
            ps2 += a2; pq2 += a2 * a2;
            ps3 += a3; pq3 += a3 * a3;
            int g = membership[n];
            if (g != curg) {
                atomAddG(&pooled[curg * 64 + 4 * r + 0], pa0);
                atomAddG(&pooled[curg * 64 + 4 * r + 1], pa1);
                atomAddG(&pooled[curg * 64 + 4 * r + 2], pa2);
                atomAddG(&pooled[curg * 64 + 4 * r + 3], pa3);
                pa0 = pa1 = pa2 = pa3 = 0.f;
                curg = g;
            }
            pa0 += a0; pa1 += a1; pa2 += a2; pa3 += a3;
        }
    }
    if (q == 0 && curg >= 0) {
        atomAddG(&pooled[curg * 64 + 4 * r + 0], pa0);
        atomAddG(&pooled[curg * 64 + 4 * r + 1], pa1);
        atomAddG(&pooled[curg * 64 + 4 * r + 2], pa2);
        atomAddG(&pooled[curg * 64 + 4 * r + 3], pa3);
    }

    if (q == 0) {
        red[w][4 * r + 0] = ps0; red[w][4 * r + 1] = ps1;
        red[w][4 * r + 2] = ps2; red[w][4 * r + 3] = ps3;
    }
    __syncthreads();
    if (w == 0) atomAddG(&sums[lane], red[0][lane] + red[1][lane] + red[2][lane] + red[3][lane]);
    __syncthreads();
    if (q == 0) {
        red[w][4 * r + 0] = pq0; red[w][4 * r + 1] = pq1;
        red[w][4 * r + 2] = pq2; red[w][4 * r + 3] = pq3;
    }
    __syncthreads();
    if (w == 0) atomAddG(&sumsq[lane], red[0][lane] + red[1][lane] + red[2][lane] + red[3][lane]);
}

// ---- head fused: pm = BN2(pooled/cnt); z = BN3(relu(pm@W_fc1+b_fc1)); out = z@W_fc2+b ----
__global__ __launch_bounds__(1024) void fc12_kernel(
    const float* __restrict__ pooled, const int* __restrict__ gstart,
    const float* __restrict__ scale2, const float* __restrict__ shift2,
    const float* __restrict__ W_fc1, const float* __restrict__ b_fc1,
    const float* __restrict__ g3, const float* __restrict__ b3,
    const float* __restrict__ W_fc2, const float* __restrict__ b_fc2,
    float* __restrict__ z, float* __restrict__ out)
{
    __shared__ float pm[4096];
    __shared__ float reds[4][256], redq[4][256];
    __shared__ float lsc[256], lsh[256];
    const int t = threadIdx.x;
    for (int i = t; i < 4096; i += 1024) {
        int g = i >> 6, f = i & 63;
        float c = fmaxf((float)(gstart[g + 1] - gstart[g]), 1.0f);
        pm[i] = fmaf(pooled[i] / c, scale2[f], shift2[f]);
    }
    __syncthreads();
    const int col = t & 255, grp = t >> 8;
    float acc[16];
    const float bc = b_fc1[col];
    #pragma unroll
    for (int g = 0; g < 16; ++g) acc[g] = bc;
    for (int k = 0; k < 64; ++k) {
        float wv = W_fc1[k * 256 + col];
        #pragma unroll
        for (int g = 0; g < 16; ++g)
            acc[g] = fmaf(pm[(grp * 16 + g) * 64 + k], wv, acc[g]);
    }
    float s = 0.f, q = 0.f;
    #pragma unroll
    for (int g = 0; g < 16; ++g) {
        acc[g] = fmaxf(acc[g], 0.f);
        s += acc[g]; q += acc[g] * acc[g];
    }
    reds[grp][col] = s; redq[grp][col] = q;
    __syncthreads();
    if (grp == 0) {
        float S = reds[0][col] + reds[1][col] + reds[2][col] + reds[3][col];
        float Q = redq[0][col] + redq[1][col] + redq[2][col] + redq[3][col];
        float m = S * (1.0f / 64.0f);
        float v = Q * (1.0f / 64.0f) - m * m;
        float sc = g3[col] * rsqrtf(v + EPSV);
        lsc[col] = sc;
        lsh[col] = b3[col] - m * sc;
    }
    __syncthreads();
    float sc = lsc[col], sh = lsh[col];
    #pragma unroll
    for (int g = 0; g < 16; ++g)
        z[(grp * 16 + g) * 256 + col] = fmaf(acc[g], sc, sh);
    __syncthreads();
    if (t < 640) {
        int g = t / 10, o = t % 10;
        float a = b_fc2[o];
        for (int c = 0; c < 256; ++c)
            a = fmaf(z[g * 256 + c], W_fc2[c * 10 + o], a);
        out[g * 10 + o] = a;
    }
}

extern "C" void kernel_launch(void* const* d_in, const int* in_sizes, int n_in,
                              void* d_out, int out_size, void* d_ws, size_t ws_size,
                              hipStream_t stream) {
    const int N = 100000, E = 1600000;

    const float* x          = (const float*)d_in[0];
    const int*   membership = (const int*)d_in[1];
    const int*   edges      = (const int*)d_in[2];
    const float* W_rel1     = (const float*)d_in[3];
    const float* b_rel1     = (const float*)d_in[4];
    const float* W_root1    = (const float*)d_in[5];
    const float* W_rel2     = (const float*)d_in[6];
    const float* b_rel2     = (const float*)d_in[7];
    const float* W_root2    = (const float*)d_in[8];
    const float* g1         = (const float*)d_in[9];
    const float* b1         = (const float*)d_in[10];
    const float* g2         = (const float*)d_in[11];
    const float* b2         = (const float*)d_in[12];
    const float* W_fc1      = (const float*)d_in[13];
    const float* b_fc1      = (const float*)d_in[14];
    const float* g3         = (const float*)d_in[15];
    const float* b3         = (const float*)d_in[16];
    const float* W_fc2      = (const float*)d_in[17];
    const float* b_fc2      = (const float*)d_in[18];

    // workspace layout (4B elements)
    int*   wsi      = (int*)d_ws;
    float* wsf      = (float*)d_ws;
    int*   gbcnt    = wsi + 0;        // 784
    float* stats    = wsf + 784;      // 512
    float* pooled   = wsf + 1296;     // 4096
    int*   bbase    = wsi + 5392;     // 800 (NB+1)
    int*   gcursor  = wsi + 6192;     // 784
    int*   gstart   = wsi + 6976;     // 128
    int*   rowstart = wsi + 7104;     // 100064
    int*   pk       = wsi + 107168;   // 1600000
    int*   srcs     = wsi + 1707168;  // 1600000
    float* agg1     = wsf + 3307168;  // 300032
    unsigned short* u1b = (unsigned short*)(wsf + 3607200);
    unsigned short* tb  = (unsigned short*)(wsf + 6807200);
    unsigned short* pb  = (unsigned short*)(wsf + 10007200);
    unsigned short* wrelp  = (unsigned short*)(wsf + 13207200);
    unsigned short* wrootp = (unsigned short*)(wsf + 13209248);
    float* crel     = wsf + 13211296; // 64
    float* croot    = wsf + 13211360; // 64
    float* z        = wsf + 13211424; // 16384

    float* sums1  = stats + 0;
    float* sumsq1 = stats + 64;
    float* sums2  = stats + 128;
    float* sumsq2 = stats + 192;
    float* scale2 = stats + 384;
    float* shift2 = stats + 448;

    hipMemsetAsync(d_ws, 0, (size_t)(784 + 512 + 4096) * 4, stream);

    // fine single-level CSR build (round-7 scheme)
    const int EB = (E + 4095) / 4096;  // 391
    bhist_kernel<<<EB, 256, 0, stream>>>(edges, gbcnt, E);
    bscan_kernel<<<1, 256, 0, stream>>>(gbcnt, bbase, gcursor, E);
    bfill_kernel<<<EB, 256, 0, stream>>>(edges, gcursor, pk, E);
    bsort_kernel<<<NB, 256, 0, stream>>>(pk, bbase, x, rowstart, srcs, agg1, N, E);
    bounds_kernel<<<(N + 256) / 256, 256, 0, stream>>>(membership, gstart, N);

    // layer 1 dense + BN1-stats
    layer1_kernel<<<(N + 127) / 128, 256, 0, stream>>>(
        x, agg1, W_rel1, b_rel1, W_root1, u1b, sums1, sumsq1, N);

    // fused BN1 scale/shift + weight fold, then MFMA transform
    bnfold_kernel<<<1, 256, 0, stream>>>(sums1, sumsq1, g1, b1,
                                         W_rel2, W_root2, b_rel2,
                                         wrelp, wrootp, crel, croot, 1.0f / N);
    mfma_transform_kernel<<<512, 256, 0, stream>>>(
        u1b, wrelp, wrootp, crel, croot, tb, pb, N / 16);

    // streaming bf16 gather + pool (4 edges/instruction)
    {
        const int GRID2 = 2048;
        int chunk = (N + GRID2 * 4 - 1) / (GRID2 * 4);  // 13
        gatherpool_kernel<<<GRID2, 256, 0, stream>>>(
            tb, pb, rowstart, srcs, membership, pooled, sums2, sumsq2, N, chunk);
    }
    bnscale_kernel<<<1, 64, 0, stream>>>(sums2, sumsq2, g2, b2, 1.0f / N, 64, scale2, shift2);

    // fused head
    fc12_kernel<<<1, 1024, 0, stream>>>(pooled, gstart, scale2, shift2,
                                        W_fc1, b_fc1, g3, b3, W_fc2, b_fc2,
                                        z, (float*)d_out);
}